// Round 17
// baseline (399.040 us; speedup 1.0000x reference)
//
#include <hip/hip_runtime.h>

#define SG 128
#define C 32
#define NPB 250000
#define BATCH 2
#define M (BATCH * NPB)
#define MP 500032            // M padded to multiple of 64
#define NW (MP / 64)         // 7813 groups of 64 points
#define NK 27
#define NBKT 65536           // {b,x/4,y/4,z/4} buckets
#define CAP 256              // max unique neighbor rows per group
#define HSZ 512              // hash table size (build kernel LDS)

typedef __attribute__((ext_vector_type(4))) float f32x4;
typedef __attribute__((ext_vector_type(8))) short bf16x8;

union frag_u { unsigned u[4]; bf16x8 v; };

__device__ __forceinline__ int bucket_key(int b, int x, int y, int z) {
    return (b << 15) | ((x >> 2) << 10) | ((y >> 2) << 5) | (z >> 2);
}

__device__ __forceinline__ void gl_lds16(const void* g, void* l) {
    __builtin_amdgcn_global_load_lds(
        (const __attribute__((address_space(1))) unsigned int*)g,
        (__attribute__((address_space(3))) unsigned int*)l, 16, 0, 0);
}

__device__ __forceinline__ void split1(float v, unsigned short& h, unsigned short& lo) {
    unsigned u = __float_as_uint(v);
    h = (unsigned short)(u >> 16);
    float hf = __uint_as_float(u & 0xFFFF0000u);
    lo = (unsigned short)(__float_as_uint(v - hf) >> 16);
}

// ---------------- counting sort: histogram ----------------
__global__ void hist_kernel(const int* __restrict__ coords, int* __restrict__ hist) {
    int p = blockIdx.x * blockDim.x + threadIdx.x;
    if (p >= M) return;
    int x = coords[3 * p + 0], y = coords[3 * p + 1], z = coords[3 * p + 2];
    atomicAdd(&hist[bucket_key(p >= NPB, x, y, z)], 1);
}

// ---------------- parallel exclusive scan (3 stages) ----------------
__global__ __launch_bounds__(256) void scan1_kernel(int* __restrict__ h, int* __restrict__ bsum) {
    __shared__ int s[256];
    int t = threadIdx.x, b = blockIdx.x;
    int v = h[b * 256 + t];
    s[t] = v;
    __syncthreads();
    for (int off = 1; off < 256; off <<= 1) {
        int x = (t >= off) ? s[t - off] : 0;
        __syncthreads();
        s[t] += x;
        __syncthreads();
    }
    h[b * 256 + t] = s[t] - v;              // exclusive within block
    if (t == 255) bsum[b] = s[255];
}
__global__ __launch_bounds__(256) void scan2_kernel(int* __restrict__ bsum) {
    __shared__ int s[256];
    int t = threadIdx.x;
    int v = bsum[t];
    s[t] = v;
    __syncthreads();
    for (int off = 1; off < 256; off <<= 1) {
        int x = (t >= off) ? s[t - off] : 0;
        __syncthreads();
        s[t] += x;
        __syncthreads();
    }
    bsum[t] = s[t] - v;                     // exclusive block offsets
}
__global__ __launch_bounds__(256) void scan3_kernel(int* __restrict__ h, const int* __restrict__ bsum) {
    h[blockIdx.x * 256 + threadIdx.x] += bsum[blockIdx.x];
}

// ------ place + feature-pack fused: sort position, grid scatter, split -------
__global__ void place_kernel(const int* __restrict__ coords, const float* __restrict__ f,
                             int* __restrict__ h, int* __restrict__ ord,
                             int* __restrict__ gridP, unsigned short* __restrict__ fpk) {
    int p = blockIdx.x * blockDim.x + threadIdx.x;
    if (p >= M) return;
    int x = coords[3 * p + 0], y = coords[3 * p + 1], z = coords[3 * p + 2];
    int b = (p >= NPB) ? 1 : 0;
    int j = atomicAdd(&h[bucket_key(b, x, y, z)], 1);
    ord[j] = p;
    gridP[((b * SG + x) * SG + y) * SG + z] = j;
    const f32x4* src = (const f32x4*)(f + (size_t)p * 32);
    unsigned short* dst = fpk + (size_t)j * 64;
#pragma unroll
    for (int c4 = 0; c4 < 8; c4++) {
        f32x4 v = src[c4];
        ushort4 hh, lo;
        split1(v[0], hh.x, lo.x);
        split1(v[1], hh.y, lo.y);
        split1(v[2], hh.z, lo.z);
        split1(v[3], hh.w, lo.w);
        *(ushort4*)(dst + c4 * 4) = hh;
        *(ushort4*)(dst + 32 + c4 * 4) = lo;
    }
}

// ------- fused neighbor-build + dedup: one wave per 64-pt group --------------
// Slots: 0 = zero row; 1..64 = the group's own points (pre-seeded, fixed);
// 65+ = external neighbors. k=13 (self tap) needs no probe. Slot renumbering
// is a permutation -> conv output identical.
__global__ __launch_bounds__(64) void build_dedup_kernel(
    const int* __restrict__ coords, const int* __restrict__ ord,
    const int* __restrict__ gridP,
    unsigned char* __restrict__ nbL, int* __restrict__ uniq, int* __restrict__ ucnt)
{
    __shared__ int hkey[HSZ];
    __shared__ int hval[HSZ];
    __shared__ int hcnt;
    const int t = threadIdx.x;           // 64 threads = 1 wave
    const int w = blockIdx.x;
    for (int i = t; i < HSZ; i += 64) { hkey[i] = -2; hval[i] = -1; }
    if (t == 0) { hcnt = 65; uniq[w * CAP] = -1; }
    __syncthreads();

    const int j = w * 64 + t;
    int x = 0, y = 0, z = 0, base = 0;
    const bool real = (j < M);
    if (real) {
        int p = ord[j];
        x = coords[3 * p + 0]; y = coords[3 * p + 1]; z = coords[3 * p + 2];
        base = (p >= NPB) ? SG * SG * SG : 0;
    }

    // ---- pre-seed: own point at fixed slot 1+t ----
    if (real) {
        unsigned h = (((unsigned)j * 2654435761u) >> 20) & (HSZ - 1);
        for (;;) {
            int old = atomicCAS(&hkey[h], -2, j);
            if (old == -2) { hval[h] = 1 + t; uniq[w * CAP + 1 + t] = j; break; }
            h = (h + 1) & (HSZ - 1);     // old==j impossible (ids unique)
        }
    } else {
        uniq[w * CAP + 1 + t] = -1;      // pad slot stages zeros
    }
    __syncthreads();

    for (int k = 0; k < NK; k++) {
        int slot = 0;
        if (k == 13) {
            slot = real ? (1 + t) : 0;
        } else {
            int id = -1;
            if (real) {
                int nx = x + k / 9 - 1;
                int ny = y + (k / 3) % 3 - 1;
                int nz = z + (k % 3) - 1;
                if ((unsigned)nx < SG && (unsigned)ny < SG && (unsigned)nz < SG)
                    id = gridP[base + (nx * SG + ny) * SG + nz];
            }
            if (id >= 0) {
                unsigned h = (((unsigned)id * 2654435761u) >> 20) & (HSZ - 1);
                slot = -1;
                while (slot < 0) {
                    int old = atomicCAS(&hkey[h], -2, id);
                    bool won = (old == -2);
                    int myslot = -1;
                    if (won) myslot = atomicAdd(&hcnt, 1);
                    if (won) {
                        if (myslot < CAP) { hval[h] = myslot; uniq[w * CAP + myslot] = id; slot = myslot; }
                        else { hval[h] = 0; slot = 0; }
                    } else if (old == id) {
                        int v = hval[h];
                        if (v >= 0) slot = v;
                    } else {
                        h = (h + 1) & (HSZ - 1);
                    }
                }
            }
        }
        nbL[((size_t)w * NK + k) * 64 + (t & 15) * 4 + (t >> 4)] = (unsigned char)slot;
    }
    __syncthreads();
    if (t == 0) ucnt[w] = (hcnt < CAP) ? hcnt : CAP;
}

// -------- pack all 3 W tensors into MFMA B-frag layout, split hi/lo ----------
// slot order per tap: 0 = bh0 (ct0 hi), 1 = bl0 (ct0 lo), 2 = bh1, 3 = bl1.
__global__ void prep_w_kernel(const float* __restrict__ W1, const float* __restrict__ W2,
                              const float* __restrict__ W3, unsigned short* __restrict__ wpk) {
    int id = blockIdx.x * blockDim.x + threadIdx.x;
    if (id >= 3 * NK * 2 * 64) return;
    int which = id / (NK * 128);
    int rid = id - which * (NK * 128);
    const float* W = which == 0 ? W1 : which == 1 ? W2 : W3;
    unsigned short* wout = wpk + (size_t)which * NK * 2048;
    int l = rid & 63, ct = (rid >> 6) & 1, k = rid >> 7;
    int lrow = l & 15, kg = l >> 4;
    unsigned hw[4], lw[4];
#pragma unroll
    for (int jp = 0; jp < 4; jp++) {
        float v0 = W[k * 1024 + (kg * 8 + 2 * jp + 0) * 32 + ct * 16 + lrow];
        float v1 = W[k * 1024 + (kg * 8 + 2 * jp + 1) * 32 + ct * 16 + lrow];
        unsigned u0 = __float_as_uint(v0), u1 = __float_as_uint(v1);
        hw[jp] = (u0 >> 16) | (u1 & 0xFFFF0000u);
        float h0 = __uint_as_float(u0 & 0xFFFF0000u);
        float h1 = __uint_as_float(u1 & 0xFFFF0000u);
        lw[jp] = (__float_as_uint(v0 - h0) >> 16) | (__float_as_uint(v1 - h1) & 0xFFFF0000u);
    }
    unsigned* dh = (unsigned*)(wout + k * 2048 + ((ct * 2 + 0) * 64 + l) * 8);
    unsigned* dl = (unsigned*)(wout + k * 2048 + ((ct * 2 + 1) * 64 + l) * 8);
#pragma unroll
    for (int i = 0; i < 4; i++) { dh[i] = hw[i]; dl[i] = lw[i]; }
}

// ------- conv: block = one 64-pt group, 4 waves (r15 structure) --------------
// Waves split taps 7/7/7/6 over all 64 rows; W double-buffered 1 tap ahead;
// MFMA phase-major with s_setprio(1) around the cluster; stage-skip for rows
// >= cnt; dump/reduce in reused LDS. nbL is u8 slots.
template <bool RELU, bool LAST>
__global__ __launch_bounds__(256) void conv_mfma(
    const unsigned short* __restrict__ fpk,  // [MP][64] packed hi|lo (physical)
    const unsigned char* __restrict__ nbL,   // [NW][27][64] u8 slot indices
    const int* __restrict__ uniq,            // [NW][CAP] physical row ids
    const int* __restrict__ ucnt,            // [NW]
    const unsigned short* __restrict__ wpk,  // packed B-frags
    const unsigned short* __restrict__ zrow, // 128 B of zeros
    const int* __restrict__ ord,             // physical -> logical (LAST only)
    unsigned short* __restrict__ opk,        // [MP][64] if !LAST
    float* __restrict__ of32)                // [M][32] if LAST (scattered)
{
    __shared__ char bufA[CAP * 128];         // 32 KB staged rows / reduce reuse

    const int t = threadIdx.x;
    const int l = t & 63;
    const int wv = t >> 6;
    const int lrow = l & 15, kg = l >> 4;
    const int w = blockIdx.x;
    const int wbase = w * 64;

    // ---- stage: only rows < cnt (rows >= cnt are never referenced) ----
    const int lane_r = l >> 3;               // row within 8-row stripe
    const int lc = l & 7;                    // chunk within row
    const int cnt = ucnt[w];
    {
        const int nneed = cnt - wv * 64;     // wave-uniform
        char* ldsb = bufA + wv * 64 * 128;
#pragma unroll
        for (int i = 0; i < 8; i++) {
            if (i * 8 < nneed) {
                int r = wv * 64 + i * 8 + lane_r;
                int id = (r < cnt) ? uniq[(size_t)w * CAP + r] : -1;
                const unsigned short* src = (id >= 0)
                    ? fpk + (size_t)id * 64 + ((lc ^ lane_r) << 3)
                    : zrow + (lc << 3);
                gl_lds16(src, ldsb + i * 1024);
            }
        }
    }

    // ---- slot preload: this wave's 7 taps into registers (u8 x4) ----
    const int kbeg = wv * 7;
    const int ntap = (wv == 3) ? 6 : 7;
    unsigned q[7];
#pragma unroll
    for (int i = 0; i < 7; i++) {
        int k = kbeg + i; if (k > 26) k = 26;
        q[i] = *(const unsigned*)(nbL + ((size_t)w * NK + k) * 64 + lrow * 4);
    }
    __builtin_amdgcn_sched_barrier(0);
    __syncthreads();                         // drains gl_lds (vmcnt) + orders LDS

    // ---- tap loop: W dbuf 1 ahead, phase-major MFMA, setprio around MFMA ----
    f32x4 acc[4][2];
#pragma unroll
    for (int rt = 0; rt < 4; rt++)
#pragma unroll
        for (int ct = 0; ct < 2; ct++) acc[rt][ct] = (f32x4){0.f, 0.f, 0.f, 0.f};

#define LOADW(DST, K) { \
    const unsigned short* wb_ = wpk + ((K) << 11); \
    DST[0].v = *(const bf16x8*)(wb_ + ((0 * 64 + l) << 3)); \
    DST[1].v = *(const bf16x8*)(wb_ + ((1 * 64 + l) << 3)); \
    DST[2].v = *(const bf16x8*)(wb_ + ((2 * 64 + l) << 3)); \
    DST[3].v = *(const bf16x8*)(wb_ + ((3 * 64 + l) << 3)); }

#define TAP(I, WCUR, WNXT) \
    if ((I) < ntap) { \
        if ((I) + 1 < ntap) LOADW(WNXT, kbeg + (I) + 1); \
        int rows[4] = {(int)(q[I] & 255), (int)((q[I] >> 8) & 255), \
                       (int)((q[I] >> 16) & 255), (int)(q[I] >> 24)}; \
        frag_u ah[4], al[4]; \
        _Pragma("unroll") \
        for (int rt = 0; rt < 4; rt++) { \
            int r = rows[rt]; \
            const char* rb = bufA + (r << 7); \
            int sw = (r & 7) << 4; \
            ah[rt].v = *(const bf16x8*)(rb + ((kg << 4) ^ sw)); \
            al[rt].v = *(const bf16x8*)(rb + (((kg + 4) << 4) ^ sw)); \
        } \
        __builtin_amdgcn_s_setprio(1); \
        _Pragma("unroll") \
        for (int rt = 0; rt < 4; rt++) acc[rt][0] = __builtin_amdgcn_mfma_f32_16x16x32_bf16(ah[rt].v, WCUR[0].v, acc[rt][0], 0, 0, 0); \
        _Pragma("unroll") \
        for (int rt = 0; rt < 4; rt++) acc[rt][1] = __builtin_amdgcn_mfma_f32_16x16x32_bf16(ah[rt].v, WCUR[2].v, acc[rt][1], 0, 0, 0); \
        _Pragma("unroll") \
        for (int rt = 0; rt < 4; rt++) acc[rt][0] = __builtin_amdgcn_mfma_f32_16x16x32_bf16(ah[rt].v, WCUR[1].v, acc[rt][0], 0, 0, 0); \
        _Pragma("unroll") \
        for (int rt = 0; rt < 4; rt++) acc[rt][1] = __builtin_amdgcn_mfma_f32_16x16x32_bf16(ah[rt].v, WCUR[3].v, acc[rt][1], 0, 0, 0); \
        _Pragma("unroll") \
        for (int rt = 0; rt < 4; rt++) acc[rt][0] = __builtin_amdgcn_mfma_f32_16x16x32_bf16(al[rt].v, WCUR[0].v, acc[rt][0], 0, 0, 0); \
        _Pragma("unroll") \
        for (int rt = 0; rt < 4; rt++) acc[rt][1] = __builtin_amdgcn_mfma_f32_16x16x32_bf16(al[rt].v, WCUR[2].v, acc[rt][1], 0, 0, 0); \
        __builtin_amdgcn_s_setprio(0); \
    }

    frag_u wA[4], wB[4];
    LOADW(wA, kbeg);
    TAP(0, wA, wB); TAP(1, wB, wA); TAP(2, wA, wB); TAP(3, wB, wA);
    TAP(4, wA, wB); TAP(5, wB, wA); TAP(6, wA, wB);
#undef TAP
#undef LOADW

    __syncthreads();                         // all A-reads done; bufA now dead

    // ---- dump partial acc into dead bufA ----
    f32x4* dmp = (f32x4*)bufA;
#pragma unroll
    for (int rt = 0; rt < 4; rt++)
#pragma unroll
        for (int ct = 0; ct < 2; ct++)
            dmp[((wv * 8 + rt * 2 + ct) << 6) + l] = acc[rt][ct];
    __syncthreads();

    // ---- distributed reduce (this wave's rt = wv) + epilogue ----
    f32x4 fin[2] = {(f32x4){0.f, 0.f, 0.f, 0.f}, (f32x4){0.f, 0.f, 0.f, 0.f}};
#pragma unroll
    for (int s = 0; s < 4; s++)
#pragma unroll
        for (int ct = 0; ct < 2; ct++)
            fin[ct] += dmp[((s * 8 + wv * 2 + ct) << 6) + l];

    const int rbase = wbase + wv * 16 + 4 * kg;
#pragma unroll
    for (int j = 0; j < 4; j++) {
        int row = rbase + j;
        if (row < M) {
            int orow = LAST ? ord[row] : row;
#pragma unroll
            for (int ct = 0; ct < 2; ct++) {
                int col = ct * 16 + lrow;
                float v = fin[ct][j];
                if (RELU) v = fmaxf(v, 0.f);
                if (LAST) {
                    of32[orow * 32 + col] = v;
                } else {
                    unsigned short h, lo;
                    split1(v, h, lo);
                    opk[row * 64 + col] = h;
                    opk[row * 64 + 32 + col] = lo;
                }
            }
        }
    }
}

extern "C" void kernel_launch(void* const* d_in, const int* in_sizes, int n_in,
                              void* d_out, int out_size, void* d_ws, size_t ws_size,
                              hipStream_t stream) {
    const float* features    = (const float*)d_in[0];
    const int*   coordinates = (const int*)d_in[1];
    const float* W1 = (const float*)d_in[4];
    const float* W2 = (const float*)d_in[5];
    const float* W3 = (const float*)d_in[6];

    char* ws = (char*)d_ws;
    const size_t GRID_BYTES = (size_t)BATCH * SG * SG * SG * 4;   // 16.78 MB
    const size_t NBL_BYTES  = (size_t)NW * NK * 64;               // 13.5 MB (u8)
    const size_t UNIQ_BYTES = (size_t)NW * CAP * 4;               // 8.0 MB
    const size_t UCNT_BYTES = (size_t)NW * 4;                     // 31 KB
    const size_t HIST_BYTES = (size_t)NBKT * 4;                   // 256 KB
    const size_t BSUM_BYTES = 256 * 4;
    const size_t ORD_BYTES  = (size_t)MP * 4;                     // 2.0 MB
    const size_t WPK_BYTES  = (size_t)NK * 2048 * 2;              // per layer
    const size_t Z_BYTES    = 256;

    size_t off = 0;
    int* gridP = (int*)(ws + off); off += GRID_BYTES;
    unsigned char* nbL = (unsigned char*)(ws + off); off += NBL_BYTES;
    int* uniq  = (int*)(ws + off); off += UNIQ_BYTES;
    int* ucnt  = (int*)(ws + off); off += UCNT_BYTES;
    int* hist  = (int*)(ws + off); off += HIST_BYTES;
    int* bsum  = (int*)(ws + off); off += BSUM_BYTES;
    int* ord   = (int*)(ws + off); off += ORD_BYTES;
    unsigned short* wpk = (unsigned short*)(ws + off); off += 3 * WPK_BYTES;
    unsigned short* zrow = (unsigned short*)(ws + off); off += Z_BYTES;
    unsigned short* fpk_a = (unsigned short*)(ws + off); off += (size_t)MP * 64 * 2; // 64 MB
    unsigned short* fpk_b = (unsigned short*)d_out;  // 64 MB, overwritten by final f32 out
    float* out = (float*)d_out;
    unsigned short* wpk1 = wpk;
    unsigned short* wpk2 = wpk + NK * 2048;
    unsigned short* wpk3 = wpk + 2 * NK * 2048;

    hipMemsetAsync(gridP, 0xFF, GRID_BYTES, stream);
    hipMemsetAsync(hist, 0, HIST_BYTES, stream);
    hipMemsetAsync(zrow, 0, Z_BYTES, stream);

    hist_kernel<<<(M + 255) / 256, 256, 0, stream>>>(coordinates, hist);
    scan1_kernel<<<256, 256, 0, stream>>>(hist, bsum);
    scan2_kernel<<<1, 256, 0, stream>>>(bsum);
    scan3_kernel<<<256, 256, 0, stream>>>(hist, bsum);
    place_kernel<<<(M + 255) / 256, 256, 0, stream>>>(coordinates, features, hist, ord, gridP, fpk_a);
    build_dedup_kernel<<<NW, 64, 0, stream>>>(coordinates, ord, gridP, nbL, uniq, ucnt);

    const int PW = 3 * NK * 2 * 64;
    prep_w_kernel<<<(PW + 255) / 256, 256, 0, stream>>>(W1, W2, W3, wpk);

    conv_mfma<true,  false><<<NW, 256, 0, stream>>>(fpk_a, nbL, uniq, ucnt, wpk1, zrow, ord, fpk_b, nullptr);
    conv_mfma<true,  false><<<NW, 256, 0, stream>>>(fpk_b, nbL, uniq, ucnt, wpk2, zrow, ord, fpk_a, nullptr);
    conv_mfma<false, true ><<<NW, 256, 0, stream>>>(fpk_a, nbL, uniq, ucnt, wpk3, zrow, ord, nullptr, out);
}

// Round 18
// 378.206 us; speedup vs baseline: 1.0551x; 1.0551x over previous
//
#include <hip/hip_runtime.h>

#define SG 128
#define C 32
#define NPB 250000
#define BATCH 2
#define M (BATCH * NPB)
#define MP 500032            // M padded to multiple of 64
#define NW (MP / 64)         // 7813 groups of 64 points
#define NK 27
#define NBKT 65536           // {b,x/4,y/4,z/4} buckets
#define CAP 256              // max unique neighbor rows per group
#define HSZ 512              // hash table size (build kernel LDS)

typedef __attribute__((ext_vector_type(4))) float f32x4;
typedef __attribute__((ext_vector_type(8))) short bf16x8;

union frag_u { unsigned u[4]; bf16x8 v; };

__device__ __forceinline__ int bucket_key(int b, int x, int y, int z) {
    return (b << 15) | ((x >> 2) << 10) | ((y >> 2) << 5) | (z >> 2);
}

__device__ __forceinline__ void gl_lds16(const void* g, void* l) {
    __builtin_amdgcn_global_load_lds(
        (const __attribute__((address_space(1))) unsigned int*)g,
        (__attribute__((address_space(3))) unsigned int*)l, 16, 0, 0);
}

__device__ __forceinline__ void split1(float v, unsigned short& h, unsigned short& lo) {
    unsigned u = __float_as_uint(v);
    h = (unsigned short)(u >> 16);
    float hf = __uint_as_float(u & 0xFFFF0000u);
    lo = (unsigned short)(__float_as_uint(v - hf) >> 16);
}

// ---------------- counting sort: histogram ----------------
__global__ void hist_kernel(const int* __restrict__ coords, int* __restrict__ hist) {
    int p = blockIdx.x * blockDim.x + threadIdx.x;
    if (p >= M) return;
    int x = coords[3 * p + 0], y = coords[3 * p + 1], z = coords[3 * p + 2];
    atomicAdd(&hist[bucket_key(p >= NPB, x, y, z)], 1);
}

// ---------------- parallel exclusive scan (3 stages) ----------------
__global__ __launch_bounds__(256) void scan1_kernel(int* __restrict__ h, int* __restrict__ bsum) {
    __shared__ int s[256];
    int t = threadIdx.x, b = blockIdx.x;
    int v = h[b * 256 + t];
    s[t] = v;
    __syncthreads();
    for (int off = 1; off < 256; off <<= 1) {
        int x = (t >= off) ? s[t - off] : 0;
        __syncthreads();
        s[t] += x;
        __syncthreads();
    }
    h[b * 256 + t] = s[t] - v;              // exclusive within block
    if (t == 255) bsum[b] = s[255];
}
__global__ __launch_bounds__(256) void scan2_kernel(int* __restrict__ bsum) {
    __shared__ int s[256];
    int t = threadIdx.x;
    int v = bsum[t];
    s[t] = v;
    __syncthreads();
    for (int off = 1; off < 256; off <<= 1) {
        int x = (t >= off) ? s[t - off] : 0;
        __syncthreads();
        s[t] += x;
        __syncthreads();
    }
    bsum[t] = s[t] - v;                     // exclusive block offsets
}
__global__ __launch_bounds__(256) void scan3_kernel(int* __restrict__ h, const int* __restrict__ bsum) {
    h[blockIdx.x * 256 + threadIdx.x] += bsum[blockIdx.x];
}

// ------ place + feature-pack fused: sort position, grid scatter, split -------
__global__ void place_kernel(const int* __restrict__ coords, const float* __restrict__ f,
                             int* __restrict__ h, int* __restrict__ ord,
                             int* __restrict__ gridP, unsigned short* __restrict__ fpk) {
    int p = blockIdx.x * blockDim.x + threadIdx.x;
    if (p >= M) return;
    int x = coords[3 * p + 0], y = coords[3 * p + 1], z = coords[3 * p + 2];
    int b = (p >= NPB) ? 1 : 0;
    int j = atomicAdd(&h[bucket_key(b, x, y, z)], 1);
    ord[j] = p;
    gridP[((b * SG + x) * SG + y) * SG + z] = j;
    const f32x4* src = (const f32x4*)(f + (size_t)p * 32);
    unsigned short* dst = fpk + (size_t)j * 64;
#pragma unroll
    for (int c4 = 0; c4 < 8; c4++) {
        f32x4 v = src[c4];
        ushort4 hh, lo;
        split1(v[0], hh.x, lo.x);
        split1(v[1], hh.y, lo.y);
        split1(v[2], hh.z, lo.z);
        split1(v[3], hh.w, lo.w);
        *(ushort4*)(dst + c4 * 4) = hh;
        *(ushort4*)(dst + 32 + c4 * 4) = lo;
    }
}

// ------- fused neighbor-build + dedup: one wave per 64-pt group --------------
// Slots: 0 = zero row; 1..64 = the group's own points (pre-seeded, fixed);
// 65+ = external neighbors. k=13 (self tap) needs no probe. Slot renumbering
// is a permutation -> conv output identical.
__global__ __launch_bounds__(64) void build_dedup_kernel(
    const int* __restrict__ coords, const int* __restrict__ ord,
    const int* __restrict__ gridP,
    unsigned char* __restrict__ nbL, int* __restrict__ uniq, int* __restrict__ ucnt)
{
    __shared__ int hkey[HSZ];
    __shared__ int hval[HSZ];
    __shared__ int hcnt;
    const int t = threadIdx.x;           // 64 threads = 1 wave
    const int w = blockIdx.x;
    for (int i = t; i < HSZ; i += 64) { hkey[i] = -2; hval[i] = -1; }
    if (t == 0) { hcnt = 65; uniq[w * CAP] = -1; }
    __syncthreads();

    const int j = w * 64 + t;
    int x = 0, y = 0, z = 0, base = 0;
    const bool real = (j < M);
    if (real) {
        int p = ord[j];
        x = coords[3 * p + 0]; y = coords[3 * p + 1]; z = coords[3 * p + 2];
        base = (p >= NPB) ? SG * SG * SG : 0;
    }

    // ---- pre-seed: own point at fixed slot 1+t ----
    if (real) {
        unsigned h = (((unsigned)j * 2654435761u) >> 20) & (HSZ - 1);
        for (;;) {
            int old = atomicCAS(&hkey[h], -2, j);
            if (old == -2) { hval[h] = 1 + t; uniq[w * CAP + 1 + t] = j; break; }
            h = (h + 1) & (HSZ - 1);     // old==j impossible (ids unique)
        }
    } else {
        uniq[w * CAP + 1 + t] = -1;      // pad slot stages zeros
    }
    __syncthreads();

    for (int k = 0; k < NK; k++) {
        int slot = 0;
        if (k == 13) {
            slot = real ? (1 + t) : 0;
        } else {
            int id = -1;
            if (real) {
                int nx = x + k / 9 - 1;
                int ny = y + (k / 3) % 3 - 1;
                int nz = z + (k % 3) - 1;
                if ((unsigned)nx < SG && (unsigned)ny < SG && (unsigned)nz < SG)
                    id = gridP[base + (nx * SG + ny) * SG + nz];
            }
            if (id >= 0) {
                unsigned h = (((unsigned)id * 2654435761u) >> 20) & (HSZ - 1);
                slot = -1;
                while (slot < 0) {
                    int old = atomicCAS(&hkey[h], -2, id);
                    bool won = (old == -2);
                    int myslot = -1;
                    if (won) myslot = atomicAdd(&hcnt, 1);
                    if (won) {
                        if (myslot < CAP) { hval[h] = myslot; uniq[w * CAP + myslot] = id; slot = myslot; }
                        else { hval[h] = 0; slot = 0; }
                    } else if (old == id) {
                        int v = hval[h];
                        if (v >= 0) slot = v;
                    } else {
                        h = (h + 1) & (HSZ - 1);
                    }
                }
            }
        }
        nbL[((size_t)w * NK + k) * 64 + (t & 15) * 4 + (t >> 4)] = (unsigned char)slot;
    }
    __syncthreads();
    if (t == 0) ucnt[w] = (hcnt < CAP) ? hcnt : CAP;
}

// -------- pack all 3 W tensors into MFMA B-frag layout, split hi/lo ----------
// slot order per tap: 0 = bh0 (ct0 hi), 1 = bl0 (ct0 lo), 2 = bh1, 3 = bl1.
__global__ void prep_w_kernel(const float* __restrict__ W1, const float* __restrict__ W2,
                              const float* __restrict__ W3, unsigned short* __restrict__ wpk) {
    int id = blockIdx.x * blockDim.x + threadIdx.x;
    if (id >= 3 * NK * 2 * 64) return;
    int which = id / (NK * 128);
    int rid = id - which * (NK * 128);
    const float* W = which == 0 ? W1 : which == 1 ? W2 : W3;
    unsigned short* wout = wpk + (size_t)which * NK * 2048;
    int l = rid & 63, ct = (rid >> 6) & 1, k = rid >> 7;
    int lrow = l & 15, kg = l >> 4;
    unsigned hw[4], lw[4];
#pragma unroll
    for (int jp = 0; jp < 4; jp++) {
        float v0 = W[k * 1024 + (kg * 8 + 2 * jp + 0) * 32 + ct * 16 + lrow];
        float v1 = W[k * 1024 + (kg * 8 + 2 * jp + 1) * 32 + ct * 16 + lrow];
        unsigned u0 = __float_as_uint(v0), u1 = __float_as_uint(v1);
        hw[jp] = (u0 >> 16) | (u1 & 0xFFFF0000u);
        float h0 = __uint_as_float(u0 & 0xFFFF0000u);
        float h1 = __uint_as_float(u1 & 0xFFFF0000u);
        lw[jp] = (__float_as_uint(v0 - h0) >> 16) | (__float_as_uint(v1 - h1) & 0xFFFF0000u);
    }
    unsigned* dh = (unsigned*)(wout + k * 2048 + ((ct * 2 + 0) * 64 + l) * 8);
    unsigned* dl = (unsigned*)(wout + k * 2048 + ((ct * 2 + 1) * 64 + l) * 8);
#pragma unroll
    for (int i = 0; i < 4; i++) { dh[i] = hw[i]; dl[i] = lw[i]; }
}

// ------- conv: block = one 64-pt group, 4 waves (r16 structure) --------------
// Waves split taps 7/7/7/6 over all 64 rows; W double-buffered 1 tap ahead;
// MFMA phase-major; stage-skip for rows >= cnt; dump/reduce in reused LDS.
// nbL is u8 slots. (No setprio: r17 showed it regresses this lockstep shape.)
template <bool RELU, bool LAST>
__global__ __launch_bounds__(256) void conv_mfma(
    const unsigned short* __restrict__ fpk,  // [MP][64] packed hi|lo (physical)
    const unsigned char* __restrict__ nbL,   // [NW][27][64] u8 slot indices
    const int* __restrict__ uniq,            // [NW][CAP] physical row ids
    const int* __restrict__ ucnt,            // [NW]
    const unsigned short* __restrict__ wpk,  // packed B-frags
    const unsigned short* __restrict__ zrow, // 128 B of zeros
    const int* __restrict__ ord,             // physical -> logical (LAST only)
    unsigned short* __restrict__ opk,        // [MP][64] if !LAST
    float* __restrict__ of32)                // [M][32] if LAST (scattered)
{
    __shared__ char bufA[CAP * 128];         // 32 KB staged rows / reduce reuse

    const int t = threadIdx.x;
    const int l = t & 63;
    const int wv = t >> 6;
    const int lrow = l & 15, kg = l >> 4;
    const int w = blockIdx.x;
    const int wbase = w * 64;

    // ---- stage: only rows < cnt (rows >= cnt are never referenced) ----
    const int lane_r = l >> 3;               // row within 8-row stripe
    const int lc = l & 7;                    // chunk within row
    const int cnt = ucnt[w];
    {
        const int nneed = cnt - wv * 64;     // wave-uniform
        char* ldsb = bufA + wv * 64 * 128;
#pragma unroll
        for (int i = 0; i < 8; i++) {
            if (i * 8 < nneed) {
                int r = wv * 64 + i * 8 + lane_r;
                int id = (r < cnt) ? uniq[(size_t)w * CAP + r] : -1;
                const unsigned short* src = (id >= 0)
                    ? fpk + (size_t)id * 64 + ((lc ^ lane_r) << 3)
                    : zrow + (lc << 3);
                gl_lds16(src, ldsb + i * 1024);
            }
        }
    }

    // ---- slot preload: this wave's 7 taps into registers (u8 x4) ----
    const int kbeg = wv * 7;
    const int ntap = (wv == 3) ? 6 : 7;
    unsigned q[7];
#pragma unroll
    for (int i = 0; i < 7; i++) {
        int k = kbeg + i; if (k > 26) k = 26;
        q[i] = *(const unsigned*)(nbL + ((size_t)w * NK + k) * 64 + lrow * 4);
    }
    __builtin_amdgcn_sched_barrier(0);
    __syncthreads();                         // drains gl_lds (vmcnt) + orders LDS

    // ---- tap loop: W dbuf 1 ahead, phase-major MFMA ----
    f32x4 acc[4][2];
#pragma unroll
    for (int rt = 0; rt < 4; rt++)
#pragma unroll
        for (int ct = 0; ct < 2; ct++) acc[rt][ct] = (f32x4){0.f, 0.f, 0.f, 0.f};

#define LOADW(DST, K) { \
    const unsigned short* wb_ = wpk + ((K) << 11); \
    DST[0].v = *(const bf16x8*)(wb_ + ((0 * 64 + l) << 3)); \
    DST[1].v = *(const bf16x8*)(wb_ + ((1 * 64 + l) << 3)); \
    DST[2].v = *(const bf16x8*)(wb_ + ((2 * 64 + l) << 3)); \
    DST[3].v = *(const bf16x8*)(wb_ + ((3 * 64 + l) << 3)); }

#define TAP(I, WCUR, WNXT) \
    if ((I) < ntap) { \
        if ((I) + 1 < ntap) LOADW(WNXT, kbeg + (I) + 1); \
        int rows[4] = {(int)(q[I] & 255), (int)((q[I] >> 8) & 255), \
                       (int)((q[I] >> 16) & 255), (int)(q[I] >> 24)}; \
        frag_u ah[4], al[4]; \
        _Pragma("unroll") \
        for (int rt = 0; rt < 4; rt++) { \
            int r = rows[rt]; \
            const char* rb = bufA + (r << 7); \
            int sw = (r & 7) << 4; \
            ah[rt].v = *(const bf16x8*)(rb + ((kg << 4) ^ sw)); \
            al[rt].v = *(const bf16x8*)(rb + (((kg + 4) << 4) ^ sw)); \
        } \
        _Pragma("unroll") \
        for (int rt = 0; rt < 4; rt++) acc[rt][0] = __builtin_amdgcn_mfma_f32_16x16x32_bf16(ah[rt].v, WCUR[0].v, acc[rt][0], 0, 0, 0); \
        _Pragma("unroll") \
        for (int rt = 0; rt < 4; rt++) acc[rt][1] = __builtin_amdgcn_mfma_f32_16x16x32_bf16(ah[rt].v, WCUR[2].v, acc[rt][1], 0, 0, 0); \
        _Pragma("unroll") \
        for (int rt = 0; rt < 4; rt++) acc[rt][0] = __builtin_amdgcn_mfma_f32_16x16x32_bf16(ah[rt].v, WCUR[1].v, acc[rt][0], 0, 0, 0); \
        _Pragma("unroll") \
        for (int rt = 0; rt < 4; rt++) acc[rt][1] = __builtin_amdgcn_mfma_f32_16x16x32_bf16(ah[rt].v, WCUR[3].v, acc[rt][1], 0, 0, 0); \
        _Pragma("unroll") \
        for (int rt = 0; rt < 4; rt++) acc[rt][0] = __builtin_amdgcn_mfma_f32_16x16x32_bf16(al[rt].v, WCUR[0].v, acc[rt][0], 0, 0, 0); \
        _Pragma("unroll") \
        for (int rt = 0; rt < 4; rt++) acc[rt][1] = __builtin_amdgcn_mfma_f32_16x16x32_bf16(al[rt].v, WCUR[2].v, acc[rt][1], 0, 0, 0); \
    }

    frag_u wA[4], wB[4];
    LOADW(wA, kbeg);
    TAP(0, wA, wB); TAP(1, wB, wA); TAP(2, wA, wB); TAP(3, wB, wA);
    TAP(4, wA, wB); TAP(5, wB, wA); TAP(6, wA, wB);
#undef TAP
#undef LOADW

    __syncthreads();                         // all A-reads done; bufA now dead

    // ---- dump partial acc into dead bufA ----
    f32x4* dmp = (f32x4*)bufA;
#pragma unroll
    for (int rt = 0; rt < 4; rt++)
#pragma unroll
        for (int ct = 0; ct < 2; ct++)
            dmp[((wv * 8 + rt * 2 + ct) << 6) + l] = acc[rt][ct];
    __syncthreads();

    // ---- distributed reduce (this wave's rt = wv) + epilogue ----
    f32x4 fin[2] = {(f32x4){0.f, 0.f, 0.f, 0.f}, (f32x4){0.f, 0.f, 0.f, 0.f}};
#pragma unroll
    for (int s = 0; s < 4; s++)
#pragma unroll
        for (int ct = 0; ct < 2; ct++)
            fin[ct] += dmp[((s * 8 + wv * 2 + ct) << 6) + l];

    const int rbase = wbase + wv * 16 + 4 * kg;
#pragma unroll
    for (int j = 0; j < 4; j++) {
        int row = rbase + j;
        if (row < M) {
            int orow = LAST ? ord[row] : row;
#pragma unroll
            for (int ct = 0; ct < 2; ct++) {
                int col = ct * 16 + lrow;
                float v = fin[ct][j];
                if (RELU) v = fmaxf(v, 0.f);
                if (LAST) {
                    of32[orow * 32 + col] = v;
                } else {
                    unsigned short h, lo;
                    split1(v, h, lo);
                    opk[row * 64 + col] = h;
                    opk[row * 64 + 32 + col] = lo;
                }
            }
        }
    }
}

extern "C" void kernel_launch(void* const* d_in, const int* in_sizes, int n_in,
                              void* d_out, int out_size, void* d_ws, size_t ws_size,
                              hipStream_t stream) {
    const float* features    = (const float*)d_in[0];
    const int*   coordinates = (const int*)d_in[1];
    const float* W1 = (const float*)d_in[4];
    const float* W2 = (const float*)d_in[5];
    const float* W3 = (const float*)d_in[6];

    char* ws = (char*)d_ws;
    const size_t GRID_BYTES = (size_t)BATCH * SG * SG * SG * 4;   // 16.78 MB
    const size_t NBL_BYTES  = (size_t)NW * NK * 64;               // 13.5 MB (u8)
    const size_t UNIQ_BYTES = (size_t)NW * CAP * 4;               // 8.0 MB
    const size_t UCNT_BYTES = (size_t)NW * 4;                     // 31 KB
    const size_t HIST_BYTES = (size_t)NBKT * 4;                   // 256 KB
    const size_t BSUM_BYTES = 256 * 4;
    const size_t ORD_BYTES  = (size_t)MP * 4;                     // 2.0 MB
    const size_t WPK_BYTES  = (size_t)NK * 2048 * 2;              // per layer
    const size_t Z_BYTES    = 256;

    size_t off = 0;
    int* gridP = (int*)(ws + off); off += GRID_BYTES;
    unsigned char* nbL = (unsigned char*)(ws + off); off += NBL_BYTES;
    int* uniq  = (int*)(ws + off); off += UNIQ_BYTES;
    int* ucnt  = (int*)(ws + off); off += UCNT_BYTES;
    int* hist  = (int*)(ws + off); off += HIST_BYTES;
    int* bsum  = (int*)(ws + off); off += BSUM_BYTES;
    int* ord   = (int*)(ws + off); off += ORD_BYTES;
    unsigned short* wpk = (unsigned short*)(ws + off); off += 3 * WPK_BYTES;
    unsigned short* zrow = (unsigned short*)(ws + off); off += Z_BYTES;
    unsigned short* fpk_a = (unsigned short*)(ws + off); off += (size_t)MP * 64 * 2; // 64 MB
    unsigned short* fpk_b = (unsigned short*)d_out;  // 64 MB, overwritten by final f32 out
    float* out = (float*)d_out;
    unsigned short* wpk1 = wpk;
    unsigned short* wpk2 = wpk + NK * 2048;
    unsigned short* wpk3 = wpk + 2 * NK * 2048;

    hipMemsetAsync(gridP, 0xFF, GRID_BYTES, stream);
    hipMemsetAsync(hist, 0, HIST_BYTES, stream);
    hipMemsetAsync(zrow, 0, Z_BYTES, stream);

    hist_kernel<<<(M + 255) / 256, 256, 0, stream>>>(coordinates, hist);
    scan1_kernel<<<256, 256, 0, stream>>>(hist, bsum);
    scan2_kernel<<<1, 256, 0, stream>>>(bsum);
    scan3_kernel<<<256, 256, 0, stream>>>(hist, bsum);
    place_kernel<<<(M + 255) / 256, 256, 0, stream>>>(coordinates, features, hist, ord, gridP, fpk_a);
    build_dedup_kernel<<<NW, 64, 0, stream>>>(coordinates, ord, gridP, nbL, uniq, ucnt);

    const int PW = 3 * NK * 2 * 64;
    prep_w_kernel<<<(PW + 255) / 256, 256, 0, stream>>>(W1, W2, W3, wpk);

    conv_mfma<true,  false><<<NW, 256, 0, stream>>>(fpk_a, nbL, uniq, ucnt, wpk1, zrow, ord, fpk_b, nullptr);
    conv_mfma<true,  false><<<NW, 256, 0, stream>>>(fpk_b, nbL, uniq, ucnt, wpk2, zrow, ord, fpk_a, nullptr);
    conv_mfma<false, true ><<<NW, 256, 0, stream>>>(fpk_a, nbL, uniq, ucnt, wpk3, zrow, ord, nullptr, out);
}